// Round 17
// baseline (133.140 us; speedup 1.0000x reference)
//
#include <hip/hip_runtime.h>
#include <hip/hip_bf16.h>

#define HID 64
#define BN_EPS 1e-5f
#define BROWS 256          // rows per bucket
#define MAXB 512           // max buckets (N <= 131072)
#define BCAP 4608          // fixed per-bucket edge capacity (mean 4096 + 8 sigma)
#define BATCH 4096         // edges per pass-A block (48 KB LDS -> 3 blocks/CU)
#define S2STRIDE 4096      // pS/pM per-feature stride (>= spmm2 grid)

typedef __attribute__((ext_vector_type(8))) short bf16x8;
typedef __attribute__((ext_vector_type(4))) float f32x4;

// ---- tiny init: zero the 512 bucket cursors ----
__global__ __launch_bounds__(512) void zero_bcur_k(int* __restrict__ bcur) {
  bcur[threadIdx.x] = 0;
}

// ------- pass A: LDS-staged binning of edges into fixed bucket regions -------
// packed entry: .x = (localrow<<17) | col,  .y = val bits
__global__ __launch_bounds__(256) void bucketA_k(
    const int* __restrict__ row, const int* __restrict__ col,
    const float* __restrict__ vals, int* __restrict__ bcur,
    int2* __restrict__ bucketed, int E, int NB) {
  __shared__ int cnt[MAXB];
  __shared__ int scn[MAXB];
  __shared__ int cnt2[MAXB];
  __shared__ int gbase[MAXB];
  __shared__ int2 stg[BATCH];
  __shared__ unsigned short stgb[BATCH];
  int t = threadIdx.x;
  int start = blockIdx.x * BATCH;
  for (int i = t; i < MAXB; i += 256) cnt[i] = 0;
  __syncthreads();
  // sub-pass 1: count
#pragma unroll
  for (int k = 0; k < BATCH / 256; ++k) {
    int i = start + k * 256 + t;
    if (i < E) atomicAdd(&cnt[row[i] >> 8], 1);
  }
  __syncthreads();
  // scan (512 entries, two indices per thread)
  int i0 = t, i1 = t + 256;
  scn[i0] = cnt[i0]; scn[i1] = cnt[i1];
  __syncthreads();
  for (int off = 1; off < 512; off <<= 1) {
    int a0 = (i0 >= off) ? scn[i0 - off] : 0;
    int a1 = (i1 >= off) ? scn[i1 - off] : 0;
    __syncthreads();
    scn[i0] += a0; scn[i1] += a1;
    __syncthreads();
  }
  cnt2[i0] = scn[i0] - cnt[i0];
  cnt2[i1] = scn[i1] - cnt[i1];
  for (int b = t; b < NB; b += 256)
    if (cnt[b] > 0) gbase[b] = atomicAdd(&bcur[b], cnt[b]);
  __syncthreads();
  // sub-pass 2: place into LDS (grouped by bucket)
#pragma unroll
  for (int k = 0; k < BATCH / 256; ++k) {
    int i = start + k * 256 + t;
    if (i < E) {
      int r = row[i];
      int b = r >> 8;
      int pos = atomicAdd(&cnt2[b], 1);
      stg[pos] = make_int2(((r & 255) << 17) | col[i], __float_as_int(vals[i]));
      stgb[pos] = (unsigned short)b;
    }
  }
  __syncthreads();
  // flush coalesced into fixed regions
  int m = min(BATCH, E - start);
  for (int s = t; s < m; s += 256) {
    int b = stgb[s];
    int lbase = scn[b] - cnt[b];
    bucketed[(size_t)b * BCAP + gbase[b] + (s - lbase)] = stg[s];
  }
}

// --- pass B (v2): single global read; load+count fused; scatter->cv fused
// with atomic-ax; then fused bn1+ReLU+W1-fold+W2 MFMA -> h2 (bf16). ----------
__global__ __launch_bounds__(256) void bucketB_k(
    const int2* __restrict__ bucketed, const int* __restrict__ bcnt,
    const float* __restrict__ x,
    const float* __restrict__ W1, const float* __restrict__ b1,
    const float* __restrict__ g, const float* __restrict__ be,
    const float* __restrict__ m, const float* __restrict__ v,
    const float* __restrict__ W2, const float* __restrict__ b2,
    int2* __restrict__ cv, int* __restrict__ rowstart, int* __restrict__ rowend,
    __hip_bfloat16* __restrict__ out, int N) {
  __shared__ int rcnt[BROWS];
  __shared__ int scn[BROWS];
  __shared__ int rcur[BROWS];
  __shared__ float axs[BROWS][4];
  __shared__ int2 stg[BCAP];
  int b = blockIdx.x;
  int t = threadIdx.x;
  int lane = t & 63;
  int wv = t >> 6;
  int li = lane & 15;
  int lk = lane >> 4;
  // ---- MFMA prologue: folded constants + W2 fragments ----
  float A0[16], A1[16], A2[16], A3[16], SS[16];
#pragma unroll
  for (int s = 0; s < 2; ++s)
#pragma unroll
    for (int j = 0; j < 8; ++j) {
      int f = 32 * s + 8 * lk + j;
      float scale = g[f] * rsqrtf(v[f] + BN_EPS);
      float shift = fmaf(-m[f], scale, be[f]);
      int idx = s * 8 + j;
      A0[idx] = scale * W1[0 * HID + f];
      A1[idx] = scale * W1[1 * HID + f];
      A2[idx] = scale * W1[2 * HID + f];
      A3[idx] = scale * b1[f];
      SS[idx] = shift;
    }
  bf16x8 bfr[4][2];
#pragma unroll
  for (int c = 0; c < 4; ++c)
#pragma unroll
    for (int s = 0; s < 2; ++s)
#pragma unroll
      for (int j = 0; j < 8; ++j) {
        int k = 32 * s + 8 * lk + j;
        __hip_bfloat16 hb = __float2bfloat16(W2[k * HID + 16 * c + li]);
        bfr[c][s][j] = *reinterpret_cast<short*>(&hb);
      }
  float b2c[4];
#pragma unroll
  for (int c = 0; c < 4; ++c) b2c[c] = b2[16 * c + li];

  // ---- init ----
  size_t rbase = (size_t)b * BCAP;
  int cnt = bcnt[b];
  int rows = min(BROWS, N - b * BROWS);
  rcnt[t] = 0;
#pragma unroll
  for (int k = 0; k < 4; ++k) axs[t][k] = 0.f;
  __syncthreads();
  // ---- pass 1: load bucket edges into LDS + count rows (single global read) -
  for (int i = t; i < cnt; i += 256) {
    int2 e = bucketed[rbase + i];
    stg[i] = e;
    atomicAdd(&rcnt[e.x >> 17], 1);
  }
  __syncthreads();
  // ---- scan ----
  scn[t] = rcnt[t];
  __syncthreads();
  for (int off = 1; off < 256; off <<= 1) {
    int vv = (t >= off) ? scn[t - off] : 0;
    __syncthreads();
    scn[t] += vv;
    __syncthreads();
  }
  int excl = scn[t] - rcnt[t];
  rcur[t] = excl;
  if (t < rows) {
    rowstart[b * BROWS + t] = (int)rbase + excl;
    rowend[b * BROWS + t] = (int)rbase + excl + rcnt[t];
  }
  __syncthreads();
  // ---- pass 2: scatter stg -> cv at sorted positions (L2-hot region, never
  // re-read here) + accumulate ax via LDS float atomics ----
  for (int i = t; i < cnt; i += 256) {
    int2 e = stg[i];
    int lr = e.x >> 17;
    int c = e.x & 0x1FFFF;
    int pos = atomicAdd(&rcur[lr], 1);
    cv[rbase + pos] = make_int2(c, e.y);
    float vv = __int_as_float(e.y);
    const float* xp = x + 3 * (size_t)c;
    atomicAdd(&axs[lr][0], vv * xp[0]);
    atomicAdd(&axs[lr][1], vv * xp[1]);
    atomicAdd(&axs[lr][2], vv * xp[2]);
    atomicAdd(&axs[lr][3], vv);
  }
  __syncthreads();
  // ---- fused MFMA: h2 rows of this bucket; wave wv does row-blocks wv*4+it --
  for (int it = 0; it < 4; ++it) {
    int rb = wv * 4 + it;
    int lrow = rb * 16 + li;
    float a0 = axs[lrow][0], a1 = axs[lrow][1],
          a2 = axs[lrow][2], a3 = axs[lrow][3];
    bf16x8 afr[2];
#pragma unroll
    for (int s = 0; s < 2; ++s)
#pragma unroll
      for (int j = 0; j < 8; ++j) {
        int idx = s * 8 + j;
        float z = fmaf(a0, A0[idx],
                  fmaf(a1, A1[idx],
                  fmaf(a2, A2[idx],
                  fmaf(a3, A3[idx], SS[idx]))));
        float u = fmaxf(z, 0.f);
        __hip_bfloat16 hb = __float2bfloat16(u);
        afr[s][j] = *reinterpret_cast<short*>(&hb);
      }
    f32x4 acc0 = {0.f, 0.f, 0.f, 0.f}, acc1 = {0.f, 0.f, 0.f, 0.f};
    f32x4 acc2 = {0.f, 0.f, 0.f, 0.f}, acc3 = {0.f, 0.f, 0.f, 0.f};
    acc0 = __builtin_amdgcn_mfma_f32_16x16x32_bf16(afr[0], bfr[0][0], acc0, 0, 0, 0);
    acc0 = __builtin_amdgcn_mfma_f32_16x16x32_bf16(afr[1], bfr[0][1], acc0, 0, 0, 0);
    acc1 = __builtin_amdgcn_mfma_f32_16x16x32_bf16(afr[0], bfr[1][0], acc1, 0, 0, 0);
    acc1 = __builtin_amdgcn_mfma_f32_16x16x32_bf16(afr[1], bfr[1][1], acc1, 0, 0, 0);
    acc2 = __builtin_amdgcn_mfma_f32_16x16x32_bf16(afr[0], bfr[2][0], acc2, 0, 0, 0);
    acc2 = __builtin_amdgcn_mfma_f32_16x16x32_bf16(afr[1], bfr[2][1], acc2, 0, 0, 0);
    acc3 = __builtin_amdgcn_mfma_f32_16x16x32_bf16(afr[0], bfr[3][0], acc3, 0, 0, 0);
    acc3 = __builtin_amdgcn_mfma_f32_16x16x32_bf16(afr[1], bfr[3][1], acc3, 0, 0, 0);
#pragma unroll
    for (int r = 0; r < 4; ++r) {
      int orow = b * BROWS + rb * 16 + 4 * lk + r;
      if (orow < N) {
        size_t ob = (size_t)orow * HID + li;
        out[ob + 0]  = __float2bfloat16(acc0[r] + b2c[0]);
        out[ob + 16] = __float2bfloat16(acc1[r] + b2c[1]);
        out[ob + 32] = __float2bfloat16(acc2[r] + b2c[2]);
        out[ob + 48] = __float2bfloat16(acc3[r] + b2c[3]);
      }
    }
  }
}

// ---- SpMM2: 8 rows/wave, 8 lanes/row, 16B (uint4) gather per lane (R12) -----
__global__ __launch_bounds__(256) void spmm2_pool_k(
    const int* __restrict__ rowstart, const int* __restrict__ rowend,
    const int2* __restrict__ cv,
    const __hip_bfloat16* __restrict__ hb,
    const float* __restrict__ g, const float* __restrict__ be,
    const float* __restrict__ m, const float* __restrict__ v,
    float* __restrict__ pS, float* __restrict__ pM, int N) {
  int lane = threadIdx.x & 63;
  int wid = threadIdx.x >> 6;
  int grp = lane >> 3;   // row slot 0..7
  int gl = lane & 7;     // feature octet
  int base = grp << 3;
  float scl[8], shf[8];
#pragma unroll
  for (int j = 0; j < 8; ++j) {
    int f = gl * 8 + j;
    float sc = g[f] * rsqrtf(v[f] + BN_EPS);
    scl[j] = sc;
    shf[j] = fmaf(-m[f], sc, be[f]);
  }
  const uint4* __restrict__ h4 = (const uint4*)hb;  // h row = 8 uint4
  float psum[8] = {0.f,0.f,0.f,0.f,0.f,0.f,0.f,0.f};
  float pmax[8] = {0.f,0.f,0.f,0.f,0.f,0.f,0.f,0.f};
  int rowstep = gridDim.x * 32;
  for (int r = blockIdx.x * 32 + wid * 8 + grp; r < N; r += rowstep) {
    int s = rowstart[r], e = rowend[r];
    float acc[8] = {0.f,0.f,0.f,0.f,0.f,0.f,0.f,0.f};
    for (int i = s; i < e; i += 8) {
      int take = e - i; if (take > 8) take = 8;
      int2 my = cv[i + (gl < take ? gl : take - 1)];
      int cj[8]; float vj[8];
#pragma unroll
      for (int j = 0; j < 8; ++j) {
        cj[j] = __shfl(my.x, base + j, 64);
        float vv = __uint_as_float((uint)__shfl(my.y, base + j, 64));
        vj[j] = (j < take) ? vv : 0.f;
      }
      uint4 hv[8];
#pragma unroll
      for (int j = 0; j < 8; ++j) hv[j] = h4[(size_t)cj[j] * 8 + gl];
#pragma unroll
      for (int j = 0; j < 8; ++j) {
        acc[0] = fmaf(vj[j], __uint_as_float(hv[j].x << 16), acc[0]);
        acc[1] = fmaf(vj[j], __uint_as_float(hv[j].x & 0xffff0000u), acc[1]);
        acc[2] = fmaf(vj[j], __uint_as_float(hv[j].y << 16), acc[2]);
        acc[3] = fmaf(vj[j], __uint_as_float(hv[j].y & 0xffff0000u), acc[3]);
        acc[4] = fmaf(vj[j], __uint_as_float(hv[j].z << 16), acc[4]);
        acc[5] = fmaf(vj[j], __uint_as_float(hv[j].z & 0xffff0000u), acc[5]);
        acc[6] = fmaf(vj[j], __uint_as_float(hv[j].w << 16), acc[6]);
        acc[7] = fmaf(vj[j], __uint_as_float(hv[j].w & 0xffff0000u), acc[7]);
      }
    }
#pragma unroll
    for (int j = 0; j < 8; ++j) {
      float hvl = fmaxf(fmaf(acc[j], scl[j], shf[j]), 0.f);
      psum[j] += hvl;
      pmax[j] = fmaxf(pmax[j], hvl);
    }
  }
  __shared__ float ls[32][HID], lm[32][HID];
  int slot = wid * 8 + grp;
#pragma unroll
  for (int j = 0; j < 8; ++j) {
    ls[slot][gl * 8 + j] = psum[j];
    lm[slot][gl * 8 + j] = pmax[j];
  }
  __syncthreads();
  int t = threadIdx.x;
  if (t < HID) {
    float s32 = 0.f, m32 = 0.f;
#pragma unroll
    for (int kk = 0; kk < 32; ++kk) {
      s32 += ls[kk][t];
      m32 = fmaxf(m32, lm[kk][t]);
    }
    pS[(size_t)t * S2STRIDE + blockIdx.x] = s32;
    pM[(size_t)t * S2STRIDE + blockIdx.x] = m32;
  }
}

// ---- reduce per-block pool partials: 64 blocks (one per feature) ------------
__global__ __launch_bounds__(256) void pool_reduce_k(
    const float* __restrict__ pS, const float* __restrict__ pM,
    float* __restrict__ gsum, float* __restrict__ gmaxf, int nblk) {
  int f = blockIdx.x;
  int t = threadIdx.x;
  float s = 0.f, m = 0.f;
  for (int j = t; j < nblk; j += 256) {
    s += pS[(size_t)f * S2STRIDE + j];
    m = fmaxf(m, pM[(size_t)f * S2STRIDE + j]);
  }
#pragma unroll
  for (int msk = 32; msk >= 1; msk >>= 1) {
    s += __shfl_xor(s, msk, 64);
    m = fmaxf(m, __shfl_xor(m, msk, 64));
  }
  __shared__ float ws_[4], wm_[4];
  if ((t & 63) == 0) { ws_[t >> 6] = s; wm_[t >> 6] = m; }
  __syncthreads();
  if (t == 0) {
    s = ws_[0] + ws_[1] + ws_[2] + ws_[3];
    m = fmaxf(fmaxf(wm_[0], wm_[1]), fmaxf(wm_[2], wm_[3]));
    gsum[f] = s;
    gmaxf[f] = m;
  }
}

// ------------- final: out = concat(mean, max) @ Wc + bc ----------------------
__global__ __launch_bounds__(128) void final_k(
    const float* __restrict__ gsum, const float* __restrict__ gmaxf,
    const float* __restrict__ Wc, const float* __restrict__ bc,
    float* __restrict__ out, float invN) {
  __shared__ float red[128 * 3];
  int j = threadIdx.x;
  float gj = (j < HID) ? gsum[j] * invN : gmaxf[j - HID];
#pragma unroll
  for (int c = 0; c < 3; ++c) red[j * 3 + c] = gj * Wc[j * 3 + c];
  __syncthreads();
  for (int off = 64; off >= 1; off >>= 1) {
    if (j < off) {
#pragma unroll
      for (int c = 0; c < 3; ++c) red[j * 3 + c] += red[(j + off) * 3 + c];
    }
    __syncthreads();
  }
  if (j < 3) out[j] = red[j] + bc[j];
}

extern "C" void kernel_launch(void* const* d_in, const int* in_sizes, int n_in,
                              void* d_out, int out_size, void* d_ws, size_t ws_size,
                              hipStream_t stream) {
  const float* x    = (const float*)d_in[0];
  const int*   row  = (const int*)d_in[1];
  const int*   col  = (const int*)d_in[2];
  const float* vals = (const float*)d_in[3];
  const float* W1   = (const float*)d_in[4];
  const float* b1   = (const float*)d_in[5];
  const float* g1   = (const float*)d_in[6];
  const float* be1  = (const float*)d_in[7];
  const float* m1   = (const float*)d_in[8];
  const float* v1   = (const float*)d_in[9];
  const float* W2   = (const float*)d_in[10];
  const float* b2   = (const float*)d_in[11];
  const float* g2   = (const float*)d_in[12];
  const float* be2  = (const float*)d_in[13];
  const float* m2   = (const float*)d_in[14];
  const float* v2   = (const float*)d_in[15];
  const float* Wc   = (const float*)d_in[16];
  const float* bc   = (const float*)d_in[17];
  float* out = (float*)d_out;

  const int N = in_sizes[0] / 3;
  const int E = in_sizes[1];
  const int NB = (N + BROWS - 1) / BROWS;
  const int S2G = (N + 31) / 32;   // spmm2 grid: one 32-row tile per block

  // ---- workspace layout ----
  __hip_bfloat16* wsA = (__hip_bfloat16*)d_ws;                // N*64 bf16 (h2, row-major)
  int2* bucketed = (int2*)(wsA + (size_t)N * HID);            // MAXB*BCAP
  int2* cv = bucketed + (size_t)MAXB * BCAP;                  // MAXB*BCAP
  int* rowstart = (int*)(cv + (size_t)MAXB * BCAP);           // N
  int* rowend = rowstart + N;                                 // N
  int* bcur = rowend + N;                                     // MAXB
  float* pS = (float*)(bcur + MAXB);                          // 64*S2STRIDE
  float* pM = pS + (size_t)HID * S2STRIDE;                    // 64*S2STRIDE
  float* gsum = pM + (size_t)HID * S2STRIDE;                  // 64
  float* gmaxf = gsum + HID;                                  // 64

  // ---- build row-sorted edge list; bucketB also emits h2 via fused MFMA ----
  zero_bcur_k<<<1, 512, 0, stream>>>(bcur);
  bucketA_k<<<(E + BATCH - 1) / BATCH, 256, 0, stream>>>(row, col, vals, bcur, bucketed, E, NB);
  bucketB_k<<<NB, 256, 0, stream>>>(bucketed, bcur, x,
                                    W1, b1, g1, be1, m1, v1, W2, b2,
                                    cv, rowstart, rowend, wsA, N);

  // ---- spmm2 fused with BN2+ReLU+pool (8 rows/wave, 16B gathers) ----
  spmm2_pool_k<<<S2G, 256, 0, stream>>>(rowstart, rowend, cv, wsA, g2, be2, m2, v2, pS, pM, N);
  pool_reduce_k<<<HID, 256, 0, stream>>>(pS, pM, gsum, gmaxf, S2G);
  // ---- out = concat(mean,max) @ Wc + bc ----
  final_k<<<1, 128, 0, stream>>>(gsum, gmaxf, Wc, bc, out, 1.0f / (float)N);
}

// Round 18
// 106.836 us; speedup vs baseline: 1.2462x; 1.2462x over previous
//
#include <hip/hip_runtime.h>
#include <hip/hip_bf16.h>

#define HID 64
#define BN_EPS 1e-5f
#define BROWS 256          // rows per bucket
#define MAXB 512           // max buckets (N <= 131072)
#define BCAP 4608          // fixed per-bucket edge capacity (mean 4096 + 8 sigma)
#define BATCH 4096         // edges per pass-A block (48 KB LDS -> 3 blocks/CU)
#define S2STRIDE 4096      // pS/pM per-feature stride (>= spmm2 grid)

typedef __attribute__((ext_vector_type(8))) short bf16x8;
typedef __attribute__((ext_vector_type(4))) float f32x4;

// ---- tiny init: zero the 512 bucket cursors + finish counter ----
__global__ __launch_bounds__(512) void zero_bcur_k(int* __restrict__ bcur,
                                                   int* __restrict__ fincnt) {
  bcur[threadIdx.x] = 0;
  if (threadIdx.x == 0) *fincnt = 0;
}

// ------- pass A: LDS-staged binning of edges into fixed bucket regions -------
// packed entry: .x = (localrow<<17) | col,  .y = val bits
__global__ __launch_bounds__(256) void bucketA_k(
    const int* __restrict__ row, const int* __restrict__ col,
    const float* __restrict__ vals, int* __restrict__ bcur,
    int2* __restrict__ bucketed, int E, int NB) {
  __shared__ int cnt[MAXB];
  __shared__ int scn[MAXB];
  __shared__ int cnt2[MAXB];
  __shared__ int gbase[MAXB];
  __shared__ int2 stg[BATCH];
  __shared__ unsigned short stgb[BATCH];
  int t = threadIdx.x;
  int start = blockIdx.x * BATCH;
  for (int i = t; i < MAXB; i += 256) cnt[i] = 0;
  __syncthreads();
  // sub-pass 1: count
#pragma unroll
  for (int k = 0; k < BATCH / 256; ++k) {
    int i = start + k * 256 + t;
    if (i < E) atomicAdd(&cnt[row[i] >> 8], 1);
  }
  __syncthreads();
  // scan (512 entries, two indices per thread)
  int i0 = t, i1 = t + 256;
  scn[i0] = cnt[i0]; scn[i1] = cnt[i1];
  __syncthreads();
  for (int off = 1; off < 512; off <<= 1) {
    int a0 = (i0 >= off) ? scn[i0 - off] : 0;
    int a1 = (i1 >= off) ? scn[i1 - off] : 0;
    __syncthreads();
    scn[i0] += a0; scn[i1] += a1;
    __syncthreads();
  }
  cnt2[i0] = scn[i0] - cnt[i0];
  cnt2[i1] = scn[i1] - cnt[i1];
  for (int b = t; b < NB; b += 256)
    if (cnt[b] > 0) gbase[b] = atomicAdd(&bcur[b], cnt[b]);
  __syncthreads();
  // sub-pass 2: place into LDS (grouped by bucket)
#pragma unroll
  for (int k = 0; k < BATCH / 256; ++k) {
    int i = start + k * 256 + t;
    if (i < E) {
      int r = row[i];
      int b = r >> 8;
      int pos = atomicAdd(&cnt2[b], 1);
      stg[pos] = make_int2(((r & 255) << 17) | col[i], __float_as_int(vals[i]));
      stgb[pos] = (unsigned short)b;
    }
  }
  __syncthreads();
  // flush coalesced into fixed regions
  int m = min(BATCH, E - start);
  for (int s = t; s < m; s += 256) {
    int b = stgb[s];
    int lbase = scn[b] - cnt[b];
    bucketed[(size_t)b * BCAP + gbase[b] + (s - lbase)] = stg[s];
  }
}

// --- pass B (R14): per-bucket LDS sort by row; cv + rowstart/rowend; ax in
// LDS; then fused bn1+ReLU+W1-fold+W2 matmul via MFMA -> h2 (bf16). ----------
__global__ __launch_bounds__(256) void bucketB_k(
    const int2* __restrict__ bucketed, const int* __restrict__ bcnt,
    const float* __restrict__ x,
    const float* __restrict__ W1, const float* __restrict__ b1,
    const float* __restrict__ g, const float* __restrict__ be,
    const float* __restrict__ m, const float* __restrict__ v,
    const float* __restrict__ W2, const float* __restrict__ b2,
    int2* __restrict__ cv, int* __restrict__ rowstart, int* __restrict__ rowend,
    __hip_bfloat16* __restrict__ out, int N) {
  __shared__ int rcnt[BROWS];
  __shared__ int scn[BROWS];
  __shared__ int rcur[BROWS];
  __shared__ float axs[BROWS][4];
  __shared__ int2 stg[BCAP];
  int b = blockIdx.x;
  int t = threadIdx.x;
  int lane = t & 63;
  int wv = t >> 6;
  int li = lane & 15;
  int lk = lane >> 4;
  // ---- MFMA prologue: folded constants + W2 fragments ----
  float A0[16], A1[16], A2[16], A3[16], SS[16];
#pragma unroll
  for (int s = 0; s < 2; ++s)
#pragma unroll
    for (int j = 0; j < 8; ++j) {
      int f = 32 * s + 8 * lk + j;
      float scale = g[f] * rsqrtf(v[f] + BN_EPS);
      float shift = fmaf(-m[f], scale, be[f]);
      int idx = s * 8 + j;
      A0[idx] = scale * W1[0 * HID + f];
      A1[idx] = scale * W1[1 * HID + f];
      A2[idx] = scale * W1[2 * HID + f];
      A3[idx] = scale * b1[f];
      SS[idx] = shift;
    }
  bf16x8 bfr[4][2];
#pragma unroll
  for (int c = 0; c < 4; ++c)
#pragma unroll
    for (int s = 0; s < 2; ++s)
#pragma unroll
      for (int j = 0; j < 8; ++j) {
        int k = 32 * s + 8 * lk + j;
        __hip_bfloat16 hb = __float2bfloat16(W2[k * HID + 16 * c + li]);
        bfr[c][s][j] = *reinterpret_cast<short*>(&hb);
      }
  float b2c[4];
#pragma unroll
  for (int c = 0; c < 4; ++c) b2c[c] = b2[16 * c + li];

  // ---- sort phase (LDS-staged; second bucketed read is L2-hot) ----
  size_t rbase = (size_t)b * BCAP;
  int cnt = bcnt[b];
  int rows = min(BROWS, N - b * BROWS);
  rcnt[t] = 0;
  __syncthreads();
  for (int i = t; i < cnt; i += 256) {
    int2 e = bucketed[rbase + i];
    atomicAdd(&rcnt[e.x >> 17], 1);
  }
  __syncthreads();
  scn[t] = rcnt[t];
  __syncthreads();
  for (int off = 1; off < 256; off <<= 1) {
    int vv = (t >= off) ? scn[t - off] : 0;
    __syncthreads();
    scn[t] += vv;
    __syncthreads();
  }
  int excl = scn[t] - rcnt[t];
  rcur[t] = excl;
  if (t < rows) {
    rowstart[b * BROWS + t] = (int)rbase + excl;
    rowend[b * BROWS + t] = (int)rbase + excl + rcnt[t];
  }
  __syncthreads();
  for (int i = t; i < cnt; i += 256) {
    int2 e = bucketed[rbase + i];
    int pos = atomicAdd(&rcur[e.x >> 17], 1);
    stg[pos] = make_int2(e.x & 0x1FFFF, e.y);
  }
  __syncthreads();
  for (int i = t; i < cnt; i += 256) cv[rbase + i] = stg[i];
  // ---- ax phase: 16-lane group per row, 16 passes ----
  int grp = t >> 4, L = t & 15;
  for (int pass = 0; pass < 16; ++pass) {
    int lrow = pass * 16 + grp;
    int s0 = scn[lrow] - rcnt[lrow];
    int e0 = scn[lrow];
    float a0 = 0.f, a1 = 0.f, a2 = 0.f, a3 = 0.f;
    for (int i2 = s0 + L; i2 < e0; i2 += 16) {
      int2 eg = stg[i2];
      const float* xp = x + 3 * (size_t)eg.x;
      float vv = __int_as_float(eg.y);
      a0 = fmaf(vv, xp[0], a0);
      a1 = fmaf(vv, xp[1], a1);
      a2 = fmaf(vv, xp[2], a2);
      a3 += vv;
    }
#pragma unroll
    for (int msk = 8; msk >= 1; msk >>= 1) {
      a0 += __shfl_xor(a0, msk, 64);
      a1 += __shfl_xor(a1, msk, 64);
      a2 += __shfl_xor(a2, msk, 64);
      a3 += __shfl_xor(a3, msk, 64);
    }
    if (L == 0) {
      axs[lrow][0] = a0; axs[lrow][1] = a1;
      axs[lrow][2] = a2; axs[lrow][3] = a3;
    }
  }
  __syncthreads();
  // ---- fused MFMA: h2 rows of this bucket; wave wv does row-blocks wv*4+it --
  for (int it = 0; it < 4; ++it) {
    int rb = wv * 4 + it;
    int lrow = rb * 16 + li;
    float a0 = axs[lrow][0], a1 = axs[lrow][1],
          a2 = axs[lrow][2], a3 = axs[lrow][3];
    bf16x8 afr[2];
#pragma unroll
    for (int s = 0; s < 2; ++s)
#pragma unroll
      for (int j = 0; j < 8; ++j) {
        int idx = s * 8 + j;
        float z = fmaf(a0, A0[idx],
                  fmaf(a1, A1[idx],
                  fmaf(a2, A2[idx],
                  fmaf(a3, A3[idx], SS[idx]))));
        float u = fmaxf(z, 0.f);
        __hip_bfloat16 hb = __float2bfloat16(u);
        afr[s][j] = *reinterpret_cast<short*>(&hb);
      }
    f32x4 acc0 = {0.f, 0.f, 0.f, 0.f}, acc1 = {0.f, 0.f, 0.f, 0.f};
    f32x4 acc2 = {0.f, 0.f, 0.f, 0.f}, acc3 = {0.f, 0.f, 0.f, 0.f};
    acc0 = __builtin_amdgcn_mfma_f32_16x16x32_bf16(afr[0], bfr[0][0], acc0, 0, 0, 0);
    acc0 = __builtin_amdgcn_mfma_f32_16x16x32_bf16(afr[1], bfr[0][1], acc0, 0, 0, 0);
    acc1 = __builtin_amdgcn_mfma_f32_16x16x32_bf16(afr[0], bfr[1][0], acc1, 0, 0, 0);
    acc1 = __builtin_amdgcn_mfma_f32_16x16x32_bf16(afr[1], bfr[1][1], acc1, 0, 0, 0);
    acc2 = __builtin_amdgcn_mfma_f32_16x16x32_bf16(afr[0], bfr[2][0], acc2, 0, 0, 0);
    acc2 = __builtin_amdgcn_mfma_f32_16x16x32_bf16(afr[1], bfr[2][1], acc2, 0, 0, 0);
    acc3 = __builtin_amdgcn_mfma_f32_16x16x32_bf16(afr[0], bfr[3][0], acc3, 0, 0, 0);
    acc3 = __builtin_amdgcn_mfma_f32_16x16x32_bf16(afr[1], bfr[3][1], acc3, 0, 0, 0);
#pragma unroll
    for (int r = 0; r < 4; ++r) {
      int orow = b * BROWS + rb * 16 + 4 * lk + r;
      if (orow < N) {
        size_t ob = (size_t)orow * HID + li;
        out[ob + 0]  = __float2bfloat16(acc0[r] + b2c[0]);
        out[ob + 16] = __float2bfloat16(acc1[r] + b2c[1]);
        out[ob + 32] = __float2bfloat16(acc2[r] + b2c[2]);
        out[ob + 48] = __float2bfloat16(acc3[r] + b2c[3]);
      }
    }
  }
}

// ---- SpMM2: 8 rows/wave, 8 lanes/row, 16B (uint4) gather per lane (R12) -----
__global__ __launch_bounds__(256) void spmm2_pool_k(
    const int* __restrict__ rowstart, const int* __restrict__ rowend,
    const int2* __restrict__ cv,
    const __hip_bfloat16* __restrict__ hb,
    const float* __restrict__ g, const float* __restrict__ be,
    const float* __restrict__ m, const float* __restrict__ v,
    float* __restrict__ pS, float* __restrict__ pM, int N) {
  int lane = threadIdx.x & 63;
  int wid = threadIdx.x >> 6;
  int grp = lane >> 3;   // row slot 0..7
  int gl = lane & 7;     // feature octet
  int base = grp << 3;
  float scl[8], shf[8];
#pragma unroll
  for (int j = 0; j < 8; ++j) {
    int f = gl * 8 + j;
    float sc = g[f] * rsqrtf(v[f] + BN_EPS);
    scl[j] = sc;
    shf[j] = fmaf(-m[f], sc, be[f]);
  }
  const uint4* __restrict__ h4 = (const uint4*)hb;  // h row = 8 uint4
  float psum[8] = {0.f,0.f,0.f,0.f,0.f,0.f,0.f,0.f};
  float pmax[8] = {0.f,0.f,0.f,0.f,0.f,0.f,0.f,0.f};
  int rowstep = gridDim.x * 32;
  for (int r = blockIdx.x * 32 + wid * 8 + grp; r < N; r += rowstep) {
    int s = rowstart[r], e = rowend[r];
    float acc[8] = {0.f,0.f,0.f,0.f,0.f,0.f,0.f,0.f};
    for (int i = s; i < e; i += 8) {
      int take = e - i; if (take > 8) take = 8;
      int2 my = cv[i + (gl < take ? gl : take - 1)];
      int cj[8]; float vj[8];
#pragma unroll
      for (int j = 0; j < 8; ++j) {
        cj[j] = __shfl(my.x, base + j, 64);
        float vv = __uint_as_float((uint)__shfl(my.y, base + j, 64));
        vj[j] = (j < take) ? vv : 0.f;
      }
      uint4 hv[8];
#pragma unroll
      for (int j = 0; j < 8; ++j) hv[j] = h4[(size_t)cj[j] * 8 + gl];
#pragma unroll
      for (int j = 0; j < 8; ++j) {
        acc[0] = fmaf(vj[j], __uint_as_float(hv[j].x << 16), acc[0]);
        acc[1] = fmaf(vj[j], __uint_as_float(hv[j].x & 0xffff0000u), acc[1]);
        acc[2] = fmaf(vj[j], __uint_as_float(hv[j].y << 16), acc[2]);
        acc[3] = fmaf(vj[j], __uint_as_float(hv[j].y & 0xffff0000u), acc[3]);
        acc[4] = fmaf(vj[j], __uint_as_float(hv[j].z << 16), acc[4]);
        acc[5] = fmaf(vj[j], __uint_as_float(hv[j].z & 0xffff0000u), acc[5]);
        acc[6] = fmaf(vj[j], __uint_as_float(hv[j].w << 16), acc[6]);
        acc[7] = fmaf(vj[j], __uint_as_float(hv[j].w & 0xffff0000u), acc[7]);
      }
    }
#pragma unroll
    for (int j = 0; j < 8; ++j) {
      float hvl = fmaxf(fmaf(acc[j], scl[j], shf[j]), 0.f);
      psum[j] += hvl;
      pmax[j] = fmaxf(pmax[j], hvl);
    }
  }
  __shared__ float ls[32][HID], lm[32][HID];
  int slot = wid * 8 + grp;
#pragma unroll
  for (int j = 0; j < 8; ++j) {
    ls[slot][gl * 8 + j] = psum[j];
    lm[slot][gl * 8 + j] = pmax[j];
  }
  __syncthreads();
  int t = threadIdx.x;
  if (t < HID) {
    float s32 = 0.f, m32 = 0.f;
#pragma unroll
    for (int kk = 0; kk < 32; ++kk) {
      s32 += ls[kk][t];
      m32 = fmaxf(m32, lm[kk][t]);
    }
    pS[(size_t)t * S2STRIDE + blockIdx.x] = s32;
    pM[(size_t)t * S2STRIDE + blockIdx.x] = m32;
  }
}

// ---- pool reduce + last-block final epilogue (64 blocks, one per feature) ---
__global__ __launch_bounds__(256) void pool_final_k(
    const float* __restrict__ pS, const float* __restrict__ pM,
    float* __restrict__ gsum, float* __restrict__ gmaxf,
    int* __restrict__ fincnt,
    const float* __restrict__ Wc, const float* __restrict__ bc,
    float* __restrict__ out, float invN, int nblk) {
  int f = blockIdx.x;
  int t = threadIdx.x;
  float s = 0.f, m = 0.f;
  for (int j = t; j < nblk; j += 256) {
    s += pS[(size_t)f * S2STRIDE + j];
    m = fmaxf(m, pM[(size_t)f * S2STRIDE + j]);
  }
#pragma unroll
  for (int msk = 32; msk >= 1; msk >>= 1) {
    s += __shfl_xor(s, msk, 64);
    m = fmaxf(m, __shfl_xor(m, msk, 64));
  }
  __shared__ float ws_[4], wm_[4];
  __shared__ int amLast;
  if ((t & 63) == 0) { ws_[t >> 6] = s; wm_[t >> 6] = m; }
  __syncthreads();
  if (t == 0) {
    s = ws_[0] + ws_[1] + ws_[2] + ws_[3];
    m = fmaxf(fmaxf(wm_[0], wm_[1]), fmaxf(wm_[2], wm_[3]));
    // device-scope publication (cross-XCD safe)
    atomicExch(&gsum[f], s);
    atomicExch(&gmaxf[f], m);
    __threadfence();
    int prev = atomicAdd(fincnt, 1);
    amLast = (prev == HID - 1);
  }
  __syncthreads();
  if (!amLast) return;
  // ---- final: out = concat(mean, max) @ Wc + bc (done by last block) ----
  __shared__ float red[128 * 3];
  int j = t;
  if (j < 128) {
    float gj = (j < HID) ? atomicAdd(&gsum[j], 0.f) * invN
                         : atomicAdd(&gmaxf[j - HID], 0.f);
#pragma unroll
    for (int c = 0; c < 3; ++c) red[j * 3 + c] = gj * Wc[j * 3 + c];
  }
  __syncthreads();
  for (int off = 64; off >= 1; off >>= 1) {
    if (j < off) {
#pragma unroll
      for (int c = 0; c < 3; ++c) red[j * 3 + c] += red[(j + off) * 3 + c];
    }
    __syncthreads();
  }
  if (j < 3) out[j] = red[j] + bc[j];
}

extern "C" void kernel_launch(void* const* d_in, const int* in_sizes, int n_in,
                              void* d_out, int out_size, void* d_ws, size_t ws_size,
                              hipStream_t stream) {
  const float* x    = (const float*)d_in[0];
  const int*   row  = (const int*)d_in[1];
  const int*   col  = (const int*)d_in[2];
  const float* vals = (const float*)d_in[3];
  const float* W1   = (const float*)d_in[4];
  const float* b1   = (const float*)d_in[5];
  const float* g1   = (const float*)d_in[6];
  const float* be1  = (const float*)d_in[7];
  const float* m1   = (const float*)d_in[8];
  const float* v1   = (const float*)d_in[9];
  const float* W2   = (const float*)d_in[10];
  const float* b2   = (const float*)d_in[11];
  const float* g2   = (const float*)d_in[12];
  const float* be2  = (const float*)d_in[13];
  const float* m2   = (const float*)d_in[14];
  const float* v2   = (const float*)d_in[15];
  const float* Wc   = (const float*)d_in[16];
  const float* bc   = (const float*)d_in[17];
  float* out = (float*)d_out;

  const int N = in_sizes[0] / 3;
  const int E = in_sizes[1];
  const int NB = (N + BROWS - 1) / BROWS;
  const int S2G = (N + 31) / 32;   // spmm2 grid: one 32-row tile per block

  // ---- workspace layout ----
  __hip_bfloat16* wsA = (__hip_bfloat16*)d_ws;                // N*64 bf16 (h2, row-major)
  int2* bucketed = (int2*)(wsA + (size_t)N * HID);            // MAXB*BCAP
  int2* cv = bucketed + (size_t)MAXB * BCAP;                  // MAXB*BCAP
  int* rowstart = (int*)(cv + (size_t)MAXB * BCAP);           // N
  int* rowend = rowstart + N;                                 // N
  int* bcur = rowend + N;                                     // MAXB
  int* fincnt = bcur + MAXB;                                  // 1 (+pad)
  float* pS = (float*)(fincnt + 2);                           // 64*S2STRIDE
  float* pM = pS + (size_t)HID * S2STRIDE;                    // 64*S2STRIDE
  float* gsum = pM + (size_t)HID * S2STRIDE;                  // 64
  float* gmaxf = gsum + HID;                                  // 64

  // ---- build row-sorted edge list; bucketB also emits h2 via fused MFMA ----
  zero_bcur_k<<<1, 512, 0, stream>>>(bcur, fincnt);
  bucketA_k<<<(E + BATCH - 1) / BATCH, 256, 0, stream>>>(row, col, vals, bcur, bucketed, E, NB);
  bucketB_k<<<NB, 256, 0, stream>>>(bucketed, bcur, x,
                                    W1, b1, g1, be1, m1, v1, W2, b2,
                                    cv, rowstart, rowend, wsA, N);

  // ---- spmm2 fused with BN2+ReLU+pool (8 rows/wave, 16B gathers) ----
  spmm2_pool_k<<<S2G, 256, 0, stream>>>(rowstart, rowend, cv, wsA, g2, be2, m2, v2, pS, pM, N);
  // ---- pool reduce + final matvec (last-block epilogue) ----
  pool_final_k<<<HID, 256, 0, stream>>>(pS, pM, gsum, gmaxf, fincnt,
                                        Wc, bc, out, 1.0f / (float)N, S2G);
}